// Round 16
// baseline (238.662 us; speedup 1.0000x reference)
//
#include <hip/hip_runtime.h>
#include <hip/hip_bf16.h>
#include <cstdint>
#include <cstddef>

typedef unsigned short u16;
typedef __attribute__((ext_vector_type(4))) unsigned short u16x4;
typedef __attribute__((ext_vector_type(8))) unsigned short u16x8;
typedef __attribute__((ext_vector_type(8))) __bf16 bf16x8;
typedef __attribute__((ext_vector_type(4))) float f32x4;

#define MFMA16(a, b, c) __builtin_amdgcn_mfma_f32_16x16x32_bf16((a), (b), (c), 0, 0, 0)

__device__ __forceinline__ u16 f2bf(float f) {
  uint32_t u = __builtin_bit_cast(uint32_t, f);
  u += 0x7FFFu + ((u >> 16) & 1u);
  return (u16)(u >> 16);
}
__device__ __forceinline__ float bf2f(u16 h) {
  return __builtin_bit_cast(float, (uint32_t)h << 16);
}

typedef const __attribute__((address_space(1))) void gv_t;
typedef __attribute__((address_space(3))) void lv_t;
__device__ __forceinline__ void gload16(const void* g, void* l) {
  __builtin_amdgcn_global_load_lds((gv_t*)g, (lv_t*)l, 16, 0, 0);
}

// ------- prep: z=0..3 -> transpose+cvt W[z]; z=4..5 -> x f32->bf16 (merged launch) -------
__global__ void prep(const float* __restrict__ x, const float* __restrict__ w0,
                     const float* __restrict__ w1, const float* __restrict__ w2,
                     const float* __restrict__ w3, u16* __restrict__ xb,
                     u16* __restrict__ wtbase) {
  const int z = blockIdx.z;
  const int bx = blockIdx.x, by = blockIdx.y;
  const int tx = threadIdx.x, ty = threadIdx.y;
  if (z >= 4) {
    const int i = ((z - 4) * 4096 + by * 64 + bx) * 256 + ty * 32 + tx;
    float4 v = ((const float4*)x)[i];
    u16x4 o;
    o[0] = f2bf(v.x); o[1] = f2bf(v.y); o[2] = f2bf(v.z); o[3] = f2bf(v.w);
    ((u16x4*)xb)[i] = o;
    return;
  }
  __shared__ float tile[32][33];
  const float* in = (z == 0) ? w0 : (z == 1) ? w1 : (z == 2) ? w2 : w3;
  u16* out = wtbase + (size_t)z * 4194304;
#pragma unroll
  for (int i = 0; i < 32; i += 8)
    tile[ty + i][tx] = in[(size_t)(by * 32 + ty + i) * 2048 + bx * 32 + tx];
  __syncthreads();
#pragma unroll
  for (int i = 0; i < 32; i += 8)
    out[(size_t)(bx * 32 + ty + i) * 2048 + by * 32 + tx] = f2bf(tile[tx][ty + i]);
}

// ============ fine-phase GEMM: C[M,*] = A[M,2048] * Bt[*,2048]^T ============
// BM=256, BN=128, BK=64, 512 threads (8 waves: 4M x 2N, per-wave 64x64).
// 3-deep LDS pipeline, counted vmcnt(6) once per K-tile. Per K-tile: 4 FINE phases
// of 8 MFMA each: {ds_read subtile + gload issue -> s_barrier -> lgkmcnt(0) +
// sched_barrier(0) -> setprio(1) 8xMFMA setprio(0)} (m201 skeleton). B-frags read
// once in phase 0, held in regs. T2 swizzle both-sides.
// MODE 1: f32 C.  MODE 2: bf16 QKV + fused RoPE (Q/K, log2e folded) + V-transpose.
template <int MODE>
__global__ __launch_bounds__(512, 1) void gemm8(const u16* __restrict__ A,
                                                const u16* __restrict__ Bt,
                                                void* __restrict__ Cv,
                                                const int* __restrict__ pos, int nbn) {
  constexpr int K = 2048;
  __shared__ __align__(16) u16 lds[73728];  // 3 x (A 32KB + B 16KB) = 144KB
  const int tid = threadIdx.x, lane = tid & 63;
  const int lo16 = lane & 15, hi = lane >> 4;
  const int wid = tid >> 6;
  const int wr = wid >> 1, wc = wid & 1;

  const int xcd = (int)blockIdx.x & 7;
  const int idx = (int)blockIdx.x >> 3;
  const int cpx = nbn >> 3;
  const int bn = (xcd * cpx + idx % cpx) * 128;
  const int bm = (idx / cpx) * 256;

  const int srow = tid >> 3;
  const int scol = ((tid & 7) ^ (srow & 7)) * 8;
  const u16* Arow = A + (size_t)(bm + srow) * K + scol;
  const u16* Brow = Bt + (size_t)(bn + srow) * K + scol;
  char* dstbase = (char*)lds + tid * 16;

#define STG_A(qb_, t_, r_) \
  gload16(Arow + (size_t)(r_) * 64 * K + (t_) * 64, dstbase + (qb_) * 49152 + (r_) * 8192)
#define STG_B(qb_, t_, r_) \
  gload16(Brow + (size_t)(r_) * 64 * K + (t_) * 64, dstbase + (qb_) * 49152 + 32768 + (r_) * 8192)

  f32x4 acc[4][4];
  const f32x4 z4 = {0.f, 0.f, 0.f, 0.f};
#pragma unroll
  for (int m = 0; m < 4; ++m)
#pragma unroll
    for (int n = 0; n < 4; ++n) acc[m][n] = z4;

  const int xork = lo16 & 7;
  const int aRow = (wr * 64 + lo16) * 128;
  const int bRow = 32768 + (wc * 64 + lo16) * 128;
  const int x0 = ((hi ^ xork)) << 4;
  const int x1 = (((4 + hi) ^ xork)) << 4;

  // prologue: stage tiles 0 and 1 (FIFO order preserved: 6 loads per tile)
  STG_A(0, 0, 0); STG_A(0, 0, 1); STG_B(0, 0, 0); STG_A(0, 0, 2); STG_A(0, 0, 3); STG_B(0, 0, 1);
  STG_A(1, 1, 0); STG_A(1, 1, 1); STG_B(1, 1, 0); STG_A(1, 1, 2); STG_A(1, 1, 3); STG_B(1, 1, 1);

  int q = 0;
  for (int t = 0; t < 32; ++t) {
    if (t < 31) {
      asm volatile("s_waitcnt vmcnt(6)" ::: "memory");  // tile t's 6 loads landed
    } else {
      asm volatile("s_waitcnt vmcnt(0)" ::: "memory");
    }
    __builtin_amdgcn_s_barrier();          // entry: tile t resident for all waves
    __builtin_amdgcn_sched_barrier(0);
    const char* Aq = (const char*)lds + q * 49152;
    const int q2 = (q == 0) ? 2 : q - 1;   // buffer for tile t+2
    const bool stg = (t < 30);

    bf16x8 b0[4], b1[4];

    // ---- phase 0: read all B (8) + A m=0 (2); stage 2; bar; lgkm0; 8 MFMA ----
    {
      bf16x8 a0, a1;
#pragma unroll
      for (int n = 0; n < 4; ++n) b0[n] = *(const bf16x8*)(Aq + bRow + n * 2048 + x0);
#pragma unroll
      for (int n = 0; n < 4; ++n) b1[n] = *(const bf16x8*)(Aq + bRow + n * 2048 + x1);
      a0 = *(const bf16x8*)(Aq + aRow + 0 * 2048 + x0);
      a1 = *(const bf16x8*)(Aq + aRow + 0 * 2048 + x1);
      if (stg) { STG_A(q2, t + 2, 0); STG_A(q2, t + 2, 1); }
      __builtin_amdgcn_sched_barrier(0);
      __builtin_amdgcn_s_barrier();
      asm volatile("s_waitcnt lgkmcnt(0)" ::: "memory");
      __builtin_amdgcn_sched_barrier(0);
      __builtin_amdgcn_s_setprio(1);
#pragma unroll
      for (int n = 0; n < 4; ++n) acc[0][n] = MFMA16(a0, b0[n], acc[0][n]);
#pragma unroll
      for (int n = 0; n < 4; ++n) acc[0][n] = MFMA16(a1, b1[n], acc[0][n]);
      __builtin_amdgcn_s_setprio(0);
    }
    // ---- phase 1: read A m=1; stage 2; bar; lgkm0; 8 MFMA ----
    {
      bf16x8 a0 = *(const bf16x8*)(Aq + aRow + 1 * 2048 + x0);
      bf16x8 a1 = *(const bf16x8*)(Aq + aRow + 1 * 2048 + x1);
      if (stg) { STG_B(q2, t + 2, 0); STG_A(q2, t + 2, 2); }
      __builtin_amdgcn_sched_barrier(0);
      __builtin_amdgcn_s_barrier();
      asm volatile("s_waitcnt lgkmcnt(0)" ::: "memory");
      __builtin_amdgcn_sched_barrier(0);
      __builtin_amdgcn_s_setprio(1);
#pragma unroll
      for (int n = 0; n < 4; ++n) acc[1][n] = MFMA16(a0, b0[n], acc[1][n]);
#pragma unroll
      for (int n = 0; n < 4; ++n) acc[1][n] = MFMA16(a1, b1[n], acc[1][n]);
      __builtin_amdgcn_s_setprio(0);
    }
    // ---- phase 2: read A m=2; stage 1; bar; lgkm0; 8 MFMA ----
    {
      bf16x8 a0 = *(const bf16x8*)(Aq + aRow + 2 * 2048 + x0);
      bf16x8 a1 = *(const bf16x8*)(Aq + aRow + 2 * 2048 + x1);
      if (stg) { STG_A(q2, t + 2, 3); }
      __builtin_amdgcn_sched_barrier(0);
      __builtin_amdgcn_s_barrier();
      asm volatile("s_waitcnt lgkmcnt(0)" ::: "memory");
      __builtin_amdgcn_sched_barrier(0);
      __builtin_amdgcn_s_setprio(1);
#pragma unroll
      for (int n = 0; n < 4; ++n) acc[2][n] = MFMA16(a0, b0[n], acc[2][n]);
#pragma unroll
      for (int n = 0; n < 4; ++n) acc[2][n] = MFMA16(a1, b1[n], acc[2][n]);
      __builtin_amdgcn_s_setprio(0);
    }
    // ---- phase 3: read A m=3; stage 1; bar; lgkm0; 8 MFMA ----
    {
      bf16x8 a0 = *(const bf16x8*)(Aq + aRow + 3 * 2048 + x0);
      bf16x8 a1 = *(const bf16x8*)(Aq + aRow + 3 * 2048 + x1);
      if (stg) { STG_B(q2, t + 2, 1); }
      __builtin_amdgcn_sched_barrier(0);
      __builtin_amdgcn_s_barrier();
      asm volatile("s_waitcnt lgkmcnt(0)" ::: "memory");
      __builtin_amdgcn_sched_barrier(0);
      __builtin_amdgcn_s_setprio(1);
#pragma unroll
      for (int n = 0; n < 4; ++n) acc[3][n] = MFMA16(a0, b0[n], acc[3][n]);
#pragma unroll
      for (int n = 0; n < 4; ++n) acc[3][n] = MFMA16(a1, b1[n], acc[3][n]);
      __builtin_amdgcn_s_setprio(0);
    }
    q = (q == 2) ? 0 : q + 1;
  }
#undef STG_A
#undef STG_B

  // ---- epilogue (unchanged) ----
  if constexpr (MODE == 2) {
    const int sect = bn >> 11;
    u16* Cq = (u16*)Cv + (size_t)sect * 8388608;
    const int cb = (bn & 2047) + wc * 64;
    if (sect < 2) {
      const float qsc = (sect == 0) ? 0.12751743f : 1.0f;  // 1/sqrt(dk) * log2(e) fold
      float freq[4];
#pragma unroll
      for (int n = 0; n < 4; ++n) {
        const int c = cb + n * 16 + lo16;
        freq[n] = exp2f((float)((c & 127) >> 1) * -0.2076205059304601f);
      }
      const float sg = (lo16 & 1) ? 1.f : -1.f;
#pragma unroll
      for (int m = 0; m < 4; ++m) {
        const int row = bm + wr * 64 + m * 16 + hi * 4;
#pragma unroll
        for (int r = 0; r < 4; ++r) {
          const float p = (float)pos[row + r];
#pragma unroll
          for (int n = 0; n < 4; ++n) {
            const float ang = p * freq[n];
            const float sn = __sinf(ang);
            const float cs = __cosf(ang);
            const float v = acc[m][n][r];
            const float pv = __shfl_xor(v, 1);
            Cq[(size_t)(row + r) * 2048 + cb + n * 16 + lo16] =
                f2bf((v * cs + sg * pv * sn) * qsc);
          }
        }
      }
    } else {
      __syncthreads();
#pragma unroll
      for (int m = 0; m < 4; ++m) {
#pragma unroll
        for (int n = 0; n < 4; ++n) {
          const int d = wc * 64 + n * 16 + lo16;
          const int tokb = wr * 64 + m * 16 + hi * 4;
#pragma unroll
          for (int r = 0; r < 4; ++r)
            lds[d * 260 + tokb + r] = f2bf(acc[m][n][r]);
        }
      }
      __syncthreads();
      const int b = bm >> 11, hh = (bn & 2047) >> 7;
      u16* vt = Cq + ((size_t)((b * 16 + hh) * 128)) * 2048 + (bm & 2047);
#pragma unroll
      for (int j = 0; j < 4; ++j) {
        const int d = (tid >> 4) + j * 32;
        const int t0 = (tid & 15) * 16;
        const u16* src = lds + d * 260 + t0;
        u16* dst = vt + (size_t)d * 2048 + t0;
#pragma unroll
        for (int w = 0; w < 4; ++w)
          *(u16x4*)(dst + w * 4) = *(const u16x4*)(src + w * 4);
      }
    }
  } else {
    float* C = (float*)Cv;
    const int cb = bn + wc * 64;
#pragma unroll
    for (int m = 0; m < 4; ++m)
#pragma unroll
      for (int n = 0; n < 4; ++n)
#pragma unroll
        for (int r = 0; r < 4; ++r)
          C[(size_t)(bm + wr * 64 + m * 16 + hi * 4 + r) * 2048 + cb + n * 16 + lo16] =
              acc[m][n][r];
  }
}

// ---- softmax (exp2 domain) + truncating P write; per-lane l partials ----
__device__ __forceinline__ void sm_write(f32x4* accS, float* m_r, float* l_r,
                                         f32x4* accO, char* Pw, int lane) {
  float lm[4];
#pragma unroll
  for (int j = 0; j < 4; ++j)
    lm[j] = fmaxf(fmaxf(accS[0][j], accS[1][j]), fmaxf(accS[2][j], accS[3][j]));
  const bool ok = (lm[0] <= m_r[0] + 11.5f) && (lm[1] <= m_r[1] + 11.5f) &&
                  (lm[2] <= m_r[2] + 11.5f) && (lm[3] <= m_r[3] + 11.5f);
  if (!__all(ok)) {
#pragma unroll
    for (int j = 0; j < 4; ++j) {
      float mx = lm[j];
#pragma unroll
      for (int off = 1; off < 16; off <<= 1) mx = fmaxf(mx, __shfl_xor(mx, off));
      const float mn = fmaxf(m_r[j], mx);
      const float sc = exp2f(m_r[j] - mn);
      m_r[j] = mn;
      l_r[j] *= sc;
#pragma unroll
      for (int db = 0; db < 8; ++db) accO[db][j] *= sc;
    }
  }
#pragma unroll
  for (int j = 0; j < 4; ++j) {
    float s = 0.f;
    const int ql = (lane >> 4) * 4 + j;
#pragma unroll
    for (int nb = 0; nb < 4; ++nb) {
      const float p = exp2f(accS[nb][j] - m_r[j]);
      s += p;
      const int col = nb * 16 + (lane & 15);
      const int byteoff = ql * 128 + ((((col >> 3) ^ (ql & 7))) << 4) + (col & 7) * 2;
      *(u16*)(Pw + byteoff) = (u16)(__builtin_bit_cast(uint32_t, p) >> 16);
    }
    l_r[j] += s;
  }
}

// ------------- causal flash attention v9 (frozen; unchanged from round 15) -------------
__global__ __launch_bounds__(256, 2) void flash_attn9(const u16* __restrict__ Qb,
                                                      const u16* __restrict__ Kb,
                                                      const u16* __restrict__ VT,
                                                      u16* __restrict__ Ob) {
  constexpr int S = 2048, HD = 2048;
  const int g = (int)blockIdx.x;
  const int xcd = g & 7, slot = g >> 3;
  const int bh = xcd * 4 + (slot & 3);
  const int pairid = slot >> 2;
  const int b = bh >> 4, h = bh & 15;
  const int tid = threadIdx.x, lane = tid & 63, wid = tid >> 6;
  const int qtA = 31 - pairid, qtB = pairid;
  const int q0a = qtA * 64, q0b = qtB * 64;

  __shared__ u16 Ks[2][64 * 128];
  __shared__ u16 Vs[2][128 * 64];
  __shared__ u16 Ps[4][2][16 * 64];

  const size_t base = (size_t)b * S * HD + (size_t)h * 128;
  const u16* Qp = Qb + base;
  const u16* Kp = Kb + base;
  const u16* VTp = VT + (size_t)bh * 128 * S;
  u16* Op = Ob + base;

  const f32x4 z4 = {0.f, 0.f, 0.f, 0.f};
  const int kKv = (lane >> 4);
  const int kC16 = (lane & 15);
  const int vD = (lane >> 3);
  const int vC16 = (lane & 7);

#define STAGE(pb, kv0_)                                                                   \
  {                                                                                       \
    _Pragma("unroll") for (int c = 0; c < 4; ++c) {                                       \
      const int ch = wid * 4 + c;                                                         \
      {                                                                                   \
        const int kv = ch * 4 + kKv;                                                      \
        const int c16 = kC16 ^ (kv & 7);                                                  \
        gload16(Kp + (size_t)((kv0_) + kv) * HD + c16 * 8, (char*)Ks[pb] + ch * 1024);    \
      }                                                                                   \
      {                                                                                   \
        const int d = ch * 8 + vD;                                                        \
        const int c16 = vC16 ^ (d & 7);                                                   \
        gload16(VTp + (size_t)d * S + (kv0_) + c16 * 8, (char*)Vs[pb] + ch * 1024);       \
      }                                                                                   \
    }                                                                                     \
  }

  bf16x8 qfA[4], qfB[4];
  {
    const int kc = (lane >> 4) * 8;
    const int qrA = q0a + wid * 16 + (lane & 15);
    const int qrB = q0b + wid * 16 + (lane & 15);
#pragma unroll
    for (int kb = 0; kb < 4; ++kb) {
      qfA[kb] = *(const bf16x8*)(Qp + (size_t)qrA * HD + kb * 32 + kc);
      qfB[kb] = *(const bf16x8*)(Qp + (size_t)qrB * HD + kb * 32 + kc);
    }
  }

  f32x4 accOA[8], accOB[8];
#pragma unroll
  for (int d = 0; d < 8; ++d) { accOA[d] = z4; accOB[d] = z4; }
  float mA[4] = {-INFINITY, -INFINITY, -INFINITY, -INFINITY};
  float lA[4] = {0.f, 0.f, 0.f, 0.f};
  float mB[4] = {-INFINITY, -INFINITY, -INFINITY, -INFINITY};
  float lB[4] = {0.f, 0.f, 0.f, 0.f};

  const int qrow0A = q0a + wid * 16 + (lane >> 4) * 4;
  const int qrow0B = q0b + wid * 16 + (lane >> 4) * 4;
  char* Pw0 = (char*)&Ps[wid][0][0];
  char* Pw1 = (char*)&Ps[wid][1][0];

  STAGE(0, 0);

  int t = 0;
  for (; t <= qtB; ++t) {
    const int cur = t & 1;
    const int kv0 = t * 64;
    STAGE(cur ^ 1, kv0 + 64);
    asm volatile("s_waitcnt vmcnt(8)" ::: "memory");
    __builtin_amdgcn_s_barrier();
    __builtin_amdgcn_sched_barrier(0);

    const char* Ksc = (const char*)Ks[cur];
    const char* Vsc = (const char*)Vs[cur];

    f32x4 sA[4], sB[4];
#pragma unroll
    for (int nb = 0; nb < 4; ++nb) { sA[nb] = z4; sB[nb] = z4; }
    __builtin_amdgcn_s_setprio(1);
#pragma unroll
    for (int nb = 0; nb < 4; ++nb) {
      const int kv = nb * 16 + (lane & 15);
#pragma unroll
      for (int kb = 0; kb < 4; ++kb) {
        const int c16 = (kb * 4 + (lane >> 4)) ^ (kv & 7);
        bf16x8 kf = *(const bf16x8*)(Ksc + kv * 256 + c16 * 16);
        sA[nb] = MFMA16(qfA[kb], kf, sA[nb]);
        sB[nb] = MFMA16(qfB[kb], kf, sB[nb]);
      }
    }
    __builtin_amdgcn_s_setprio(0);

    if (t == qtB) {
#pragma unroll
      for (int nb = 0; nb < 4; ++nb) {
        const int kv = kv0 + nb * 16 + (lane & 15);
#pragma unroll
        for (int j = 0; j < 4; ++j)
          if (kv > qrow0B + j) sB[nb][j] = -INFINITY;
      }
    }

    sm_write(sA, mA, lA, accOA, Pw0, lane);
    sm_write(sB, mB, lB, accOB, Pw1, lane);

#pragma unroll
    for (int kb2 = 0; kb2 < 2; ++kb2) {
      const int ql = lane & 15;
      const int c16a = (kb2 * 4 + (lane >> 4)) ^ (ql & 7);
      bf16x8 paA = *(const bf16x8*)(Pw0 + ql * 128 + c16a * 16);
      bf16x8 paB = *(const bf16x8*)(Pw1 + ql * 128 + c16a * 16);
      __builtin_amdgcn_s_setprio(1);
#pragma unroll
      for (int db = 0; db < 8; ++db) {
        const int d = db * 16 + (lane & 15);
        const int c16 = (kb2 * 4 + (lane >> 4)) ^ (d & 7);
        bf16x8 vf = *(const bf16x8*)(Vsc + d * 128 + c16 * 16);
        accOA[db] = MFMA16(paA, vf, accOA[db]);
        accOB[db] = MFMA16(paB, vf, accOB[db]);
      }
      __builtin_amdgcn_s_setprio(0);
    }
    __builtin_amdgcn_sched_barrier(0);
    __builtin_amdgcn_s_barrier();
  }

  for (; t <= qtA; ++t) {
    const int cur = t & 1;
    const int kv0 = t * 64;
    if (t < qtA) {
      STAGE(cur ^ 1, kv0 + 64);
      asm volatile("s_waitcnt vmcnt(8)" ::: "memory");
    } else {
      asm volatile("s_waitcnt vmcnt(0)" ::: "memory");
    }
    __builtin_amdgcn_s_barrier();
    __builtin_amdgcn_sched_barrier(0);

    const char* Ksc = (const char*)Ks[cur];
    const char* Vsc = (const char*)Vs[cur];

    f32x4 sA[4];
#pragma unroll
    for (int nb = 0; nb < 4; ++nb) sA[nb] = z4;
    __builtin_amdgcn_s_setprio(1);
#pragma unroll
    for (int nb = 0; nb < 4; ++nb) {
      const int kv = nb * 16 + (lane & 15);
#pragma unroll
      for (int kb = 0; kb < 4; ++kb) {
        const int c16 = (kb * 4 + (lane >> 4)) ^ (kv & 7);
        bf16x8 kf = *(const bf16x8*)(Ksc + kv * 256 + c16 * 16);
        sA[nb] = MFMA16(qfA[kb], kf, sA[nb]);
      }
    }
    __builtin_amdgcn_s_setprio(0);

    if (t == qtA) {
#pragma unroll
      for (int nb = 0; nb < 4; ++nb) {
        const int kv = kv0 + nb * 16 + (lane & 15);
#pragma unroll
        for (int j = 0; j < 4; ++j)
          if (kv > qrow0A + j) sA[nb][j] = -INFINITY;
      }
    }

    sm_write(sA, mA, lA, accOA, Pw0, lane);

#pragma unroll
    for (int kb2 = 0; kb2 < 2; ++kb2) {
      const int ql = lane & 15;
      const int c16a = (kb2 * 4 + (lane >> 4)) ^ (ql & 7);
      bf16x8 paA = *(const bf16x8*)(Pw0 + ql * 128 + c16a * 16);
      __builtin_amdgcn_s_setprio(1);
#pragma unroll
      for (int db = 0; db < 8; ++db) {
        const int d = db * 16 + (lane & 15);
        const int c16 = (kb2 * 4 + (lane >> 4)) ^ (d & 7);
        bf16x8 vf = *(const bf16x8*)(Vsc + d * 128 + c16 * 16);
        accOA[db] = MFMA16(paA, vf, accOA[db]);
      }
      __builtin_amdgcn_s_setprio(0);
    }
    __builtin_amdgcn_sched_barrier(0);
    __builtin_amdgcn_s_barrier();
  }
#undef STAGE

  float invA[4], invB[4];
#pragma unroll
  for (int j = 0; j < 4; ++j) {
    float la = lA[j], lb = lB[j];
#pragma unroll
    for (int off = 1; off < 16; off <<= 1) {
      la += __shfl_xor(la, off);
      lb += __shfl_xor(lb, off);
    }
    invA[j] = 1.f / la;
    invB[j] = 1.f / lb;
  }
#pragma unroll
  for (int db = 0; db < 8; ++db)
#pragma unroll
    for (int j = 0; j < 4; ++j) {
      const int rowA = qrow0A + j;
      const int rowB = qrow0B + j;
      Op[(size_t)rowA * HD + db * 16 + (lane & 15)] = f2bf(accOA[db][j] * invA[j]);
      Op[(size_t)rowB * HD + db * 16 + (lane & 15)] = f2bf(accOB[db][j] * invB[j]);
    }
}

extern "C" void kernel_launch(void* const* d_in, const int* in_sizes, int n_in,
                              void* d_out, int out_size, void* d_ws, size_t ws_size,
                              hipStream_t stream) {
  const float* x  = (const float*)d_in[0];
  const int*   tp = (const int*)d_in[1];
  const float* WQ = (const float*)d_in[2];
  const float* WK = (const float*)d_in[3];
  const float* WV = (const float*)d_in[4];
  const float* WO = (const float*)d_in[5];

  const size_t MB = 1024 * 1024;
  if (ws_size < 112 * MB) return;
  char* ws = (char*)d_ws;
  u16* xb  = (u16*)(ws + 0 * MB);
  u16* wqt = (u16*)(ws + 16 * MB);   // wqt/wkt/wvt/wot contiguous, 8MB each
  u16* wot = (u16*)(ws + 40 * MB);
  u16* Qb  = (u16*)(ws + 48 * MB);   // Q(48MB) K(64MB) VT(80MB) -- gemm8<2> sect offsets
  u16* Kb  = (u16*)(ws + 64 * MB);
  u16* VTb = (u16*)(ws + 80 * MB);
  u16* Obf = (u16*)(ws + 96 * MB);

  {
    dim3 g(64, 64, 6), blk(32, 8);
    prep<<<g, blk, 0, stream>>>(x, WQ, WK, WV, WO, xb, wqt);
  }
  // fused QKV projection + RoPE(+log2e fold) + V-transpose: -> Qb | Kb | VTb
  gemm8<2><<<768, 512, 0, stream>>>(xb, wqt, (void*)Qb, tp, 48);

  flash_attn9<<<512, 256, 0, stream>>>(Qb, Kb, VTb, Obf);

  // output projection -> f32 d_out
  gemm8<1><<<256, 512, 0, stream>>>(Obf, wot, d_out, nullptr, 16);
}

// Round 17
// 236.297 us; speedup vs baseline: 1.0100x; 1.0100x over previous
//
#include <hip/hip_runtime.h>
#include <hip/hip_bf16.h>
#include <cstdint>
#include <cstddef>

typedef unsigned short u16;
typedef __attribute__((ext_vector_type(4))) unsigned short u16x4;
typedef __attribute__((ext_vector_type(8))) unsigned short u16x8;
typedef __attribute__((ext_vector_type(8))) __bf16 bf16x8;
typedef __attribute__((ext_vector_type(4))) float f32x4;

#define MFMA16(a, b, c) __builtin_amdgcn_mfma_f32_16x16x32_bf16((a), (b), (c), 0, 0, 0)

__device__ __forceinline__ u16 f2bf(float f) {
  uint32_t u = __builtin_bit_cast(uint32_t, f);
  u += 0x7FFFu + ((u >> 16) & 1u);
  return (u16)(u >> 16);
}
__device__ __forceinline__ float bf2f(u16 h) {
  return __builtin_bit_cast(float, (uint32_t)h << 16);
}

typedef const __attribute__((address_space(1))) void gv_t;
typedef __attribute__((address_space(3))) void lv_t;
__device__ __forceinline__ void gload16(const void* g, void* l) {
  __builtin_amdgcn_global_load_lds((gv_t*)g, (lv_t*)l, 16, 0, 0);
}

// ------- prep: z=0..3 -> transpose+cvt W[z]; z=4..5 -> x f32->bf16 (merged launch) -------
__global__ void prep(const float* __restrict__ x, const float* __restrict__ w0,
                     const float* __restrict__ w1, const float* __restrict__ w2,
                     const float* __restrict__ w3, u16* __restrict__ xb,
                     u16* __restrict__ wtbase) {
  const int z = blockIdx.z;
  const int bx = blockIdx.x, by = blockIdx.y;
  const int tx = threadIdx.x, ty = threadIdx.y;
  if (z >= 4) {
    const int i = ((z - 4) * 4096 + by * 64 + bx) * 256 + ty * 32 + tx;
    float4 v = ((const float4*)x)[i];
    u16x4 o;
    o[0] = f2bf(v.x); o[1] = f2bf(v.y); o[2] = f2bf(v.z); o[3] = f2bf(v.w);
    ((u16x4*)xb)[i] = o;
    return;
  }
  __shared__ float tile[32][33];
  const float* in = (z == 0) ? w0 : (z == 1) ? w1 : (z == 2) ? w2 : w3;
  u16* out = wtbase + (size_t)z * 4194304;
#pragma unroll
  for (int i = 0; i < 32; i += 8)
    tile[ty + i][tx] = in[(size_t)(by * 32 + ty + i) * 2048 + bx * 32 + tx];
  __syncthreads();
#pragma unroll
  for (int i = 0; i < 32; i += 8)
    out[(size_t)(bx * 32 + ty + i) * 2048 + by * 32 + tx] = f2bf(tile[tx][ty + i]);
}

// ============ merged-phase GEMM (round-12 best: single 32-MFMA cluster, 1 barrier/K-tile) ============
// BM=256, BN=128, BK=64, 512 threads (8 waves: 4M x 2N, per-wave 64x64).
// 3-deep LDS pipeline, counted vmcnt(6). T2 swizzle both-sides. XCD B-column raster.
// MODE 1: f32 C.  MODE 2: bf16 QKV + fused RoPE (Q/K, log2e folded) + V-transpose epilogue.
template <int MODE>
__global__ __launch_bounds__(512, 1) void gemm8(const u16* __restrict__ A,
                                                const u16* __restrict__ Bt,
                                                void* __restrict__ Cv,
                                                const int* __restrict__ pos, int nbn) {
  constexpr int K = 2048;
  __shared__ __align__(16) u16 lds[73728];  // 3 x (A 32KB + B 16KB) = 144KB
  const int tid = threadIdx.x, lane = tid & 63;
  const int lo16 = lane & 15, hi = lane >> 4;
  const int wid = tid >> 6;
  const int wr = wid >> 1, wc = wid & 1;

  const int xcd = (int)blockIdx.x & 7;
  const int idx = (int)blockIdx.x >> 3;
  const int cpx = nbn >> 3;
  const int bn = (xcd * cpx + idx % cpx) * 128;
  const int bm = (idx / cpx) * 256;

  const int srow = tid >> 3;
  const int scol = ((tid & 7) ^ (srow & 7)) * 8;  // pre-swizzled source col
  const u16* Arow = A + (size_t)(bm + srow) * K + scol;
  const u16* Brow = Bt + (size_t)(bn + srow) * K + scol;
  char* dstbase = (char*)lds + tid * 16;

#define STG_A(qb_, t_, r_) \
  gload16(Arow + (size_t)(r_) * 64 * K + (t_) * 64, dstbase + (qb_) * 49152 + (r_) * 8192)
#define STG_B(qb_, t_, r_) \
  gload16(Brow + (size_t)(r_) * 64 * K + (t_) * 64, dstbase + (qb_) * 49152 + 32768 + (r_) * 8192)

  f32x4 acc[4][4];
  const f32x4 z4 = {0.f, 0.f, 0.f, 0.f};
#pragma unroll
  for (int m = 0; m < 4; ++m)
#pragma unroll
    for (int n = 0; n < 4; ++n) acc[m][n] = z4;

  const int xork = lo16 & 7;
  const int aRow = (wr * 64 + lo16) * 128;
  const int bRow = 32768 + (wc * 64 + lo16) * 128;
  const int x0 = ((hi ^ xork)) << 4;
  const int x1 = (((4 + hi) ^ xork)) << 4;

  STG_A(0, 0, 0); STG_A(0, 0, 1); STG_A(0, 0, 2); STG_A(0, 0, 3);
  STG_B(0, 0, 0); STG_B(0, 0, 1);
  STG_A(1, 1, 0); STG_A(1, 1, 1); STG_A(1, 1, 2); STG_A(1, 1, 3);
  STG_B(1, 1, 0); STG_B(1, 1, 1);

  int q = 0;
  for (int t = 0; t < 32; ++t) {
    if (t < 31) {
      asm volatile("s_waitcnt vmcnt(6)" ::: "memory");
    } else {
      asm volatile("s_waitcnt vmcnt(0)" ::: "memory");
    }
    __builtin_amdgcn_s_barrier();
    __builtin_amdgcn_sched_barrier(0);
    const char* Aq = (const char*)lds + q * 49152;
    const int q2 = (q == 0) ? 2 : q - 1;

    bf16x8 a0[4], b0[4], a1[4], b1[4];
#pragma unroll
    for (int m = 0; m < 4; ++m) a0[m] = *(const bf16x8*)(Aq + aRow + m * 2048 + x0);
#pragma unroll
    for (int n = 0; n < 4; ++n) b0[n] = *(const bf16x8*)(Aq + bRow + n * 2048 + x0);
#pragma unroll
    for (int m = 0; m < 4; ++m) a1[m] = *(const bf16x8*)(Aq + aRow + m * 2048 + x1);
#pragma unroll
    for (int n = 0; n < 4; ++n) b1[n] = *(const bf16x8*)(Aq + bRow + n * 2048 + x1);

    if (t < 30) {
      STG_A(q2, t + 2, 0); STG_A(q2, t + 2, 1); STG_A(q2, t + 2, 2); STG_A(q2, t + 2, 3);
      STG_B(q2, t + 2, 0); STG_B(q2, t + 2, 1);
    }

    __builtin_amdgcn_s_setprio(1);
#pragma unroll
    for (int m = 0; m < 4; ++m)
#pragma unroll
      for (int n = 0; n < 4; ++n) acc[m][n] = MFMA16(a0[m], b0[n], acc[m][n]);
#pragma unroll
    for (int m = 0; m < 4; ++m)
#pragma unroll
      for (int n = 0; n < 4; ++n) acc[m][n] = MFMA16(a1[m], b1[n], acc[m][n]);
    __builtin_amdgcn_s_setprio(0);
    q = (q == 2) ? 0 : q + 1;
  }
#undef STG_A
#undef STG_B

  // ---- epilogue ----
  if constexpr (MODE == 2) {
    const int sect = bn >> 11;  // 0=Q, 1=K, 2=V (buffers 16MB apart)
    u16* Cq = (u16*)Cv + (size_t)sect * 8388608;
    const int cb = (bn & 2047) + wc * 64;
    if (sect < 2) {
      const float qsc = (sect == 0) ? 0.12751743f : 1.0f;  // 1/sqrt(dk) * log2(e)
      float freq[4];
#pragma unroll
      for (int n = 0; n < 4; ++n) {
        const int c = cb + n * 16 + lo16;
        freq[n] = exp2f((float)((c & 127) >> 1) * -0.2076205059304601f);
      }
      const float sg = (lo16 & 1) ? 1.f : -1.f;
#pragma unroll
      for (int m = 0; m < 4; ++m) {
        const int row = bm + wr * 64 + m * 16 + hi * 4;
#pragma unroll
        for (int r = 0; r < 4; ++r) {
          const float p = (float)pos[row + r];
#pragma unroll
          for (int n = 0; n < 4; ++n) {
            const float ang = p * freq[n];
            const float sn = __sinf(ang);
            const float cs = __cosf(ang);
            const float v = acc[m][n][r];
            const float pv = __shfl_xor(v, 1);
            Cq[(size_t)(row + r) * 2048 + cb + n * 16 + lo16] =
                f2bf((v * cs + sg * pv * sn) * qsc);
          }
        }
      }
    } else {
      // V section: LDS-transpose, write VT [B,H,dk,S] directly
      __syncthreads();
#pragma unroll
      for (int m = 0; m < 4; ++m) {
#pragma unroll
        for (int n = 0; n < 4; ++n) {
          const int d = wc * 64 + n * 16 + lo16;
          const int tokb = wr * 64 + m * 16 + hi * 4;
#pragma unroll
          for (int r = 0; r < 4; ++r)
            lds[d * 260 + tokb + r] = f2bf(acc[m][n][r]);
        }
      }
      __syncthreads();
      const int b = bm >> 11, hh = (bn & 2047) >> 7;
      u16* vt = Cq + ((size_t)((b * 16 + hh) * 128)) * 2048 + (bm & 2047);
#pragma unroll
      for (int j = 0; j < 4; ++j) {
        const int d = (tid >> 4) + j * 32;
        const int t0 = (tid & 15) * 16;
        const u16* src = lds + d * 260 + t0;
        u16* dst = vt + (size_t)d * 2048 + t0;
#pragma unroll
        for (int w = 0; w < 4; ++w)
          *(u16x4*)(dst + w * 4) = *(const u16x4*)(src + w * 4);
      }
    }
  } else {
    float* C = (float*)Cv;
    const int cb = bn + wc * 64;
#pragma unroll
    for (int m = 0; m < 4; ++m)
#pragma unroll
      for (int n = 0; n < 4; ++n)
#pragma unroll
        for (int r = 0; r < 4; ++r)
          C[(size_t)(bm + wr * 64 + m * 16 + hi * 4 + r) * 2048 + cb + n * 16 + lo16] =
              acc[m][n][r];
  }
}

// ---- softmax (exp2 domain) + truncating P write; per-lane l partials ----
__device__ __forceinline__ void sm_write(f32x4* accS, float* m_r, float* l_r,
                                         f32x4* accO, char* Pw, int lane) {
  float lm[4];
#pragma unroll
  for (int j = 0; j < 4; ++j)
    lm[j] = fmaxf(fmaxf(accS[0][j], accS[1][j]), fmaxf(accS[2][j], accS[3][j]));
  const bool ok = (lm[0] <= m_r[0] + 11.5f) && (lm[1] <= m_r[1] + 11.5f) &&
                  (lm[2] <= m_r[2] + 11.5f) && (lm[3] <= m_r[3] + 11.5f);
  if (!__all(ok)) {
#pragma unroll
    for (int j = 0; j < 4; ++j) {
      float mx = lm[j];
#pragma unroll
      for (int off = 1; off < 16; off <<= 1) mx = fmaxf(mx, __shfl_xor(mx, off));
      const float mn = fmaxf(m_r[j], mx);
      const float sc = exp2f(m_r[j] - mn);
      m_r[j] = mn;
      l_r[j] *= sc;
#pragma unroll
      for (int db = 0; db < 8; ++db) accO[db][j] *= sc;
    }
  }
#pragma unroll
  for (int j = 0; j < 4; ++j) {
    float s = 0.f;
    const int ql = (lane >> 4) * 4 + j;
#pragma unroll
    for (int nb = 0; nb < 4; ++nb) {
      const float p = exp2f(accS[nb][j] - m_r[j]);
      s += p;
      const int col = nb * 16 + (lane & 15);
      const int byteoff = ql * 128 + ((((col >> 3) ^ (ql & 7))) << 4) + (col & 7) * 2;
      *(u16*)(Pw + byteoff) = (u16)(__builtin_bit_cast(uint32_t, p) >> 16);
    }
    l_r[j] += s;
  }
}

// ------------- causal flash attention v9 (frozen) -------------
__global__ __launch_bounds__(256, 2) void flash_attn9(const u16* __restrict__ Qb,
                                                      const u16* __restrict__ Kb,
                                                      const u16* __restrict__ VT,
                                                      u16* __restrict__ Ob) {
  constexpr int S = 2048, HD = 2048;
  const int g = (int)blockIdx.x;
  const int xcd = g & 7, slot = g >> 3;
  const int bh = xcd * 4 + (slot & 3);
  const int pairid = slot >> 2;
  const int b = bh >> 4, h = bh & 15;
  const int tid = threadIdx.x, lane = tid & 63, wid = tid >> 6;
  const int qtA = 31 - pairid, qtB = pairid;
  const int q0a = qtA * 64, q0b = qtB * 64;

  __shared__ u16 Ks[2][64 * 128];
  __shared__ u16 Vs[2][128 * 64];
  __shared__ u16 Ps[4][2][16 * 64];

  const size_t base = (size_t)b * S * HD + (size_t)h * 128;
  const u16* Qp = Qb + base;
  const u16* Kp = Kb + base;
  const u16* VTp = VT + (size_t)bh * 128 * S;
  u16* Op = Ob + base;

  const f32x4 z4 = {0.f, 0.f, 0.f, 0.f};
  const int kKv = (lane >> 4);
  const int kC16 = (lane & 15);
  const int vD = (lane >> 3);
  const int vC16 = (lane & 7);

#define STAGE(pb, kv0_)                                                                   \
  {                                                                                       \
    _Pragma("unroll") for (int c = 0; c < 4; ++c) {                                       \
      const int ch = wid * 4 + c;                                                         \
      {                                                                                   \
        const int kv = ch * 4 + kKv;                                                      \
        const int c16 = kC16 ^ (kv & 7);                                                  \
        gload16(Kp + (size_t)((kv0_) + kv) * HD + c16 * 8, (char*)Ks[pb] + ch * 1024);    \
      }                                                                                   \
      {                                                                                   \
        const int d = ch * 8 + vD;                                                        \
        const int c16 = vC16 ^ (d & 7);                                                   \
        gload16(VTp + (size_t)d * S + (kv0_) + c16 * 8, (char*)Vs[pb] + ch * 1024);       \
      }                                                                                   \
    }                                                                                     \
  }

  bf16x8 qfA[4], qfB[4];
  {
    const int kc = (lane >> 4) * 8;
    const int qrA = q0a + wid * 16 + (lane & 15);
    const int qrB = q0b + wid * 16 + (lane & 15);
#pragma unroll
    for (int kb = 0; kb < 4; ++kb) {
      qfA[kb] = *(const bf16x8*)(Qp + (size_t)qrA * HD + kb * 32 + kc);
      qfB[kb] = *(const bf16x8*)(Qp + (size_t)qrB * HD + kb * 32 + kc);
    }
  }

  f32x4 accOA[8], accOB[8];
#pragma unroll
  for (int d = 0; d < 8; ++d) { accOA[d] = z4; accOB[d] = z4; }
  float mA[4] = {-INFINITY, -INFINITY, -INFINITY, -INFINITY};
  float lA[4] = {0.f, 0.f, 0.f, 0.f};
  float mB[4] = {-INFINITY, -INFINITY, -INFINITY, -INFINITY};
  float lB[4] = {0.f, 0.f, 0.f, 0.f};

  const int qrow0A = q0a + wid * 16 + (lane >> 4) * 4;
  const int qrow0B = q0b + wid * 16 + (lane >> 4) * 4;
  char* Pw0 = (char*)&Ps[wid][0][0];
  char* Pw1 = (char*)&Ps[wid][1][0];

  STAGE(0, 0);

  int t = 0;
  for (; t <= qtB; ++t) {
    const int cur = t & 1;
    const int kv0 = t * 64;
    STAGE(cur ^ 1, kv0 + 64);
    asm volatile("s_waitcnt vmcnt(8)" ::: "memory");
    __builtin_amdgcn_s_barrier();
    __builtin_amdgcn_sched_barrier(0);

    const char* Ksc = (const char*)Ks[cur];
    const char* Vsc = (const char*)Vs[cur];

    f32x4 sA[4], sB[4];
#pragma unroll
    for (int nb = 0; nb < 4; ++nb) { sA[nb] = z4; sB[nb] = z4; }
    __builtin_amdgcn_s_setprio(1);
#pragma unroll
    for (int nb = 0; nb < 4; ++nb) {
      const int kv = nb * 16 + (lane & 15);
#pragma unroll
      for (int kb = 0; kb < 4; ++kb) {
        const int c16 = (kb * 4 + (lane >> 4)) ^ (kv & 7);
        bf16x8 kf = *(const bf16x8*)(Ksc + kv * 256 + c16 * 16);
        sA[nb] = MFMA16(qfA[kb], kf, sA[nb]);
        sB[nb] = MFMA16(qfB[kb], kf, sB[nb]);
      }
    }
    __builtin_amdgcn_s_setprio(0);

    if (t == qtB) {
#pragma unroll
      for (int nb = 0; nb < 4; ++nb) {
        const int kv = kv0 + nb * 16 + (lane & 15);
#pragma unroll
        for (int j = 0; j < 4; ++j)
          if (kv > qrow0B + j) sB[nb][j] = -INFINITY;
      }
    }

    sm_write(sA, mA, lA, accOA, Pw0, lane);
    sm_write(sB, mB, lB, accOB, Pw1, lane);

#pragma unroll
    for (int kb2 = 0; kb2 < 2; ++kb2) {
      const int ql = lane & 15;
      const int c16a = (kb2 * 4 + (lane >> 4)) ^ (ql & 7);
      bf16x8 paA = *(const bf16x8*)(Pw0 + ql * 128 + c16a * 16);
      bf16x8 paB = *(const bf16x8*)(Pw1 + ql * 128 + c16a * 16);
      __builtin_amdgcn_s_setprio(1);
#pragma unroll
      for (int db = 0; db < 8; ++db) {
        const int d = db * 16 + (lane & 15);
        const int c16 = (kb2 * 4 + (lane >> 4)) ^ (d & 7);
        bf16x8 vf = *(const bf16x8*)(Vsc + d * 128 + c16 * 16);
        accOA[db] = MFMA16(paA, vf, accOA[db]);
        accOB[db] = MFMA16(paB, vf, accOB[db]);
      }
      __builtin_amdgcn_s_setprio(0);
    }
    __builtin_amdgcn_sched_barrier(0);
    __builtin_amdgcn_s_barrier();
  }

  for (; t <= qtA; ++t) {
    const int cur = t & 1;
    const int kv0 = t * 64;
    if (t < qtA) {
      STAGE(cur ^ 1, kv0 + 64);
      asm volatile("s_waitcnt vmcnt(8)" ::: "memory");
    } else {
      asm volatile("s_waitcnt vmcnt(0)" ::: "memory");
    }
    __builtin_amdgcn_s_barrier();
    __builtin_amdgcn_sched_barrier(0);

    const char* Ksc = (const char*)Ks[cur];
    const char* Vsc = (const char*)Vs[cur];

    f32x4 sA[4];
#pragma unroll
    for (int nb = 0; nb < 4; ++nb) sA[nb] = z4;
    __builtin_amdgcn_s_setprio(1);
#pragma unroll
    for (int nb = 0; nb < 4; ++nb) {
      const int kv = nb * 16 + (lane & 15);
#pragma unroll
      for (int kb = 0; kb < 4; ++kb) {
        const int c16 = (kb * 4 + (lane >> 4)) ^ (kv & 7);
        bf16x8 kf = *(const bf16x8*)(Ksc + kv * 256 + c16 * 16);
        sA[nb] = MFMA16(qfA[kb], kf, sA[nb]);
      }
    }
    __builtin_amdgcn_s_setprio(0);

    if (t == qtA) {
#pragma unroll
      for (int nb = 0; nb < 4; ++nb) {
        const int kv = kv0 + nb * 16 + (lane & 15);
#pragma unroll
        for (int j = 0; j < 4; ++j)
          if (kv > qrow0A + j) sA[nb][j] = -INFINITY;
      }
    }

    sm_write(sA, mA, lA, accOA, Pw0, lane);

#pragma unroll
    for (int kb2 = 0; kb2 < 2; ++kb2) {
      const int ql = lane & 15;
      const int c16a = (kb2 * 4 + (lane >> 4)) ^ (ql & 7);
      bf16x8 paA = *(const bf16x8*)(Pw0 + ql * 128 + c16a * 16);
      __builtin_amdgcn_s_setprio(1);
#pragma unroll
      for (int db = 0; db < 8; ++db) {
        const int d = db * 16 + (lane & 15);
        const int c16 = (kb2 * 4 + (lane >> 4)) ^ (d & 7);
        bf16x8 vf = *(const bf16x8*)(Vsc + d * 128 + c16 * 16);
        accOA[db] = MFMA16(paA, vf, accOA[db]);
      }
      __builtin_amdgcn_s_setprio(0);
    }
    __builtin_amdgcn_sched_barrier(0);
    __builtin_amdgcn_s_barrier();
  }
#undef STAGE

  float invA[4], invB[4];
#pragma unroll
  for (int j = 0; j < 4; ++j) {
    float la = lA[j], lb = lB[j];
#pragma unroll
    for (int off = 1; off < 16; off <<= 1) {
      la += __shfl_xor(la, off);
      lb += __shfl_xor(lb, off);
    }
    invA[j] = 1.f / la;
    invB[j] = 1.f / lb;
  }
#pragma unroll
  for (int db = 0; db < 8; ++db)
#pragma unroll
    for (int j = 0; j < 4; ++j) {
      const int rowA = qrow0A + j;
      const int rowB = qrow0B + j;
      Op[(size_t)rowA * HD + db * 16 + (lane & 15)] = f2bf(accOA[db][j] * invA[j]);
      Op[(size_t)rowB * HD + db * 16 + (lane & 15)] = f2bf(accOB[db][j] * invB[j]);
    }
}

extern "C" void kernel_launch(void* const* d_in, const int* in_sizes, int n_in,
                              void* d_out, int out_size, void* d_ws, size_t ws_size,
                              hipStream_t stream) {
  const float* x  = (const float*)d_in[0];
  const int*   tp = (const int*)d_in[1];
  const float* WQ = (const float*)d_in[2];
  const float* WK = (const float*)d_in[3];
  const float* WV = (const float*)d_in[4];
  const float* WO = (const float*)d_in[5];

  const size_t MB = 1024 * 1024;
  if (ws_size < 112 * MB) return;
  char* ws = (char*)d_ws;
  u16* xb  = (u16*)(ws + 0 * MB);
  u16* wqt = (u16*)(ws + 16 * MB);   // wqt/wkt/wvt/wot contiguous, 8MB each
  u16* wot = (u16*)(ws + 40 * MB);
  u16* Qb  = (u16*)(ws + 48 * MB);   // Q(48MB) K(64MB) VT(80MB) -- gemm8<2> sect offsets
  u16* Kb  = (u16*)(ws + 64 * MB);
  u16* VTb = (u16*)(ws + 80 * MB);
  u16* Obf = (u16*)(ws + 96 * MB);

  {
    dim3 g(64, 64, 6), blk(32, 8);
    prep<<<g, blk, 0, stream>>>(x, WQ, WK, WV, WO, xb, wqt);
  }
  // fused QKV projection + RoPE(+log2e fold) + V-transpose: -> Qb | Kb | VTb
  gemm8<2><<<768, 512, 0, stream>>>(xb, wqt, (void*)Qb, tp, 48);

  flash_attn9<<<512, 256, 0, stream>>>(Qb, Kb, VTb, Obf);

  // output projection -> f32 d_out
  gemm8<1><<<256, 512, 0, stream>>>(Obf, wot, d_out, nullptr, 16);
}